// Round 8
// baseline (210.800 us; speedup 1.0000x reference)
//
#include <hip/hip_runtime.h>
#include <hip/hip_bf16.h>

// MultiHeadAttention B=4,S=4096,D=64,H=4,HD=16 on gfx950.
// softmax over QUERY axis => w[s,t] = E[s,t]/colsum[t], attended = E @ (V/colsum).
// Two MFMA passes recompute E (raw v_exp_f32).  Scores via 32x32x16 bf16 MFMA
// (K=16=HD exact).  PV consumes E directly as the B-operand; the implied k->t
// permutation is absorbed by pre-permuting v' into LDS fragment layout.
// R8: k_attn software-pipelined staging — 256-t chunks, double-buffered LDS
// (21 KB -> 7 blocks/CU), next chunk's global loads issued before compute,
// LDS writes after, 1 barrier/chunk.  R7's stage->barrier->compute serialized
// all waves of a block at every chunk boundary (28% idle).

#define BB 4
#define SS 4096
#define DD 64
#define HH 4
#define HDD 16

typedef unsigned int u32;
typedef unsigned short u16;
typedef __attribute__((ext_vector_type(8))) short bfrag;     // 8 bf16
typedef __attribute__((ext_vector_type(4))) float floatx4;
typedef __attribute__((ext_vector_type(16))) float floatx16;
typedef __attribute__((ext_vector_type(2))) u32 u32x2;
typedef __attribute__((ext_vector_type(4))) u32 u32x4;

#define LOG2E 1.4426950408889634074f
#define QSCALE (LOG2E * 0.25f)

__device__ __forceinline__ float fexp2(float x) {   // raw v_exp_f32
#if __has_builtin(__builtin_amdgcn_exp2f)
  return __builtin_amdgcn_exp2f(x);
#else
  float r; asm("v_exp_f32 %0, %1" : "=v"(r) : "v"(x)); return r;
#endif
}
__device__ __forceinline__ float frcp(float x) {    // raw v_rcp_f32
#if __has_builtin(__builtin_amdgcn_rcpf)
  return __builtin_amdgcn_rcpf(x);
#else
  float r; asm("v_rcp_f32 %0, %1" : "=v"(r) : "v"(x)); return r;
#endif
}

__device__ __forceinline__ u16 f2bf(float f) {      // RNE
  u32 u = __builtin_bit_cast(u32, f);
  return (u16)((u + 0x7FFFu + ((u >> 16) & 1u)) >> 16);
}
// pack two fp32 -> bf16x2 by truncation (E>=0), single v_perm_b32
__device__ __forceinline__ u32 pack_bf(float lo, float hi) {
#if __has_builtin(__builtin_amdgcn_perm)
  return __builtin_amdgcn_perm(__builtin_bit_cast(u32, hi),
                               __builtin_bit_cast(u32, lo), 0x07060302u);
#else
  u32 a = __builtin_bit_cast(u32, lo);
  u32 b = __builtin_bit_cast(u32, hi);
  return (a >> 16) | (b & 0xFFFF0000u);
#endif
}

// ---------------------------------------------------------------------------
// K1: projections. x[B,S,64] -> q bf16 (scaled, bias folded), k bf16, v fp32;
// layout [B,H,S,16].
// ---------------------------------------------------------------------------
__global__ __launch_bounds__(256) void k_proj(
    const float* __restrict__ x,
    const float* __restrict__ Wq, const float* __restrict__ bq,
    const float* __restrict__ Wk, const float* __restrict__ bk,
    const float* __restrict__ Wv, const float* __restrict__ bv,
    u16* __restrict__ qb, u16* __restrict__ kb, float* __restrict__ vf)
{
  __shared__ float xs[16 * 64];
  const int tid = threadIdx.x;
  const int blk = blockIdx.x;            // B*S/16 = 1024
  const int b   = blk >> 8;
  const int s0  = (blk & 255) << 4;
  ((float4*)xs)[tid] = ((const float4*)(x + ((size_t)b * SS + s0) * DD))[tid];
  __syncthreads();

  const int col = tid & 63, h = col >> 4, e = col & 15;
  const int rg  = tid >> 6;              // wave id; 4 rows each
  float aq[4] = {0,0,0,0}, ak[4] = {0,0,0,0}, av[4] = {0,0,0,0};
  const int wofs = h * (DD * HDD) + e;
#pragma unroll 4
  for (int d = 0; d < DD; ++d) {
    float wq = Wq[wofs + d * HDD];
    float wk = Wk[wofs + d * HDD];
    float wv = Wv[wofs + d * HDD];
    const float* xr = xs + (rg * 4) * 64 + d;
#pragma unroll
    for (int r = 0; r < 4; ++r) {
      float xv = xr[r * 64];
      aq[r] += xv * wq; ak[r] += xv * wk; av[r] += xv * wv;
    }
  }
  const float bqv = bq[col], bkv = bk[col], bvv = bv[col];
  size_t base = ((size_t)(b * HH + h) * SS + (s0 + rg * 4)) * HDD + e;
#pragma unroll
  for (int r = 0; r < 4; ++r) {
    qb[base + r * HDD] = f2bf((aq[r] + bqv) * QSCALE);
    kb[base + r * HDD] = f2bf(ak[r] + bkv);
    vf[base + r * HDD] = av[r] + bvv;
  }
}

// ---------------------------------------------------------------------------
// K2: partial colsums.  mfma(Q, K): D[m=s][n=t], col=lane&31 -> t, so the
// s-reduction is IN-LANE (16 adds) + one shfl_xor(32).  Wave owns 32 t;
// streams a 1024-s chunk.
// ---------------------------------------------------------------------------
__global__ __launch_bounds__(256, 8) void k_colsum(
    const u16* __restrict__ qb, const u16* __restrict__ kb,
    float* __restrict__ csp)
{
  const int tid = threadIdx.x;
  const int lane = tid & 63, w = tid >> 6;
  const int l31 = lane & 31, hl = lane >> 5;
  const int bh = blockIdx.z, chunk = blockIdx.y;
  const int t0 = blockIdx.x * 128 + w * 32;
  const size_t base = (size_t)bh * (SS * HDD);

  const bfrag kf = *(const bfrag*)(kb + base + (size_t)(t0 + l31) * HDD + hl * 8);
  const u16* qp = qb + base + (size_t)l31 * HDD + hl * 8;
  const floatx16 z16 = {0.f};
  float c = 0.f;
  const int s0 = chunk * 1024;
#pragma unroll 2
  for (int s = s0; s < s0 + 1024; s += 32) {
    bfrag qfr = *(const bfrag*)(qp + (size_t)s * HDD);
    floatx16 d = __builtin_amdgcn_mfma_f32_32x32x16_bf16(qfr, kf, z16, 0, 0, 0);
#pragma unroll
    for (int i = 0; i < 16; ++i) c += fexp2(d[i]);
  }
  c += __shfl_xor(c, 32, 64);
  if (hl == 0)
    csp[((size_t)bh * 4 + chunk) * SS + t0 + l31] = c;
}

// ---------------------------------------------------------------------------
// K3: attended partials = E @ v' over a 1024-t quarter: four 256-t chunks,
// DOUBLE-BUFFERED.  Per chunk: issue next chunk's global float4 loads into
// registers, compute 8 iters from the current LDS buffer, then scale+pack
// the prefetched regs into the other buffer; one barrier per chunk.
// rcs = rcp(colsum) built once per block for the whole quarter.
// Inner loop per 32 t: 1 coalesced kf load, 1 score MFMA D'[t][s], 16 v_exp,
// 8 v_perm packs, 2 ds_read_b128, 2 PV MFMA.  LDS 21 KB -> 7 blocks/CU.
// ---------------------------------------------------------------------------
__global__ __launch_bounds__(256, 7) void k_attn(
    const u16* __restrict__ qb, const u16* __restrict__ kb,
    const float* __restrict__ vf, const float* __restrict__ csp,
    float* __restrict__ attp)
{
  __shared__ __align__(16) u16 vls[2][16][264];    // 16,896 B (264 = 256+8 pad)
  __shared__ float rcs[1024];                      //  4,096 B
  const int tid  = threadIdx.x;
  const int lane = tid & 63, w = tid >> 6;
  const int l31 = lane & 31, hl = lane >> 5;
  const int bh = blockIdx.z, b = bh >> 2, h = bh & 3;
  const int tq = blockIdx.y;                       // 0..3
  const int s0 = blockIdx.x * 128 + w * 32;
  const size_t base = (size_t)bh * (SS * HDD);
  const int tbq = tq * 1024;

  // 1/colsum for the whole quarter (sum of 4 s-chunk partials)
  {
    const float* cp0 = csp + (size_t)bh * 4 * SS + tbq;
#pragma unroll
    for (int i = 0; i < 4; ++i) {
      int j = i * 256 + tid;
      rcs[j] = frcp(cp0[j] + cp0[j + SS] + cp0[j + 2 * SS] + cp0[j + 3 * SS]);
    }
  }
  __syncthreads();

  const bfrag qf = *(const bfrag*)(qb + base + (size_t)(s0 + l31) * HDD + hl * 8);
  const u16* kp = kb + base + (size_t)l31 * HDD + hl * 8;
  const floatx16 z16 = {0.f};
  floatx16 acc = {0.f};

  const float4* vsrc = (const float4*)(vf + base + (size_t)tbq * HDD);

  // stage chunk 0 into vls[0]
  {
#pragma unroll
    for (int kk = 0; kk < 4; ++kk) {
      int c = kk * 256 + tid;            // [0,1024): 256 t x 4 e-groups
      int tl = c >> 2, g = c & 3;
      float4 vv = vsrc[c];
      float rc = rcs[tl];
      int i5 = tl >> 5, t5 = tl & 31;
      int sub = ((t5 >> 2) & 1) * 16 + ((t5 >> 3) << 2) + (t5 & 3);
      u16* wp = &vls[0][0][0] + i5 * 32 + sub;
      wp[(4 * g + 0) * 264] = f2bf(vv.x * rc);
      wp[(4 * g + 1) * 264] = f2bf(vv.y * rc);
      wp[(4 * g + 2) * 264] = f2bf(vv.z * rc);
      wp[(4 * g + 3) * 264] = f2bf(vv.w * rc);
    }
  }
  __syncthreads();

#pragma unroll
  for (int ch = 0; ch < 4; ++ch) {
    // prefetch next chunk's global data into registers (issue before compute)
    float4 pv[4];
    if (ch < 3) {
#pragma unroll
      for (int kk = 0; kk < 4; ++kk)
        pv[kk] = vsrc[(ch + 1) * 1024 + kk * 256 + tid];
    }

    // compute 8 iters (256 t) from vls[ch&1]
    const u16* vrow = &vls[ch & 1][0][0] + (l31 & 15) * 264 + hl * 16;
    const int tb = tbq + ch * 256;
#pragma unroll 2
    for (int it = 0; it < 8; ++it) {
      bfrag kf = *(const bfrag*)(kp + (size_t)(tb + it * 32) * HDD);
      floatx16 d = __builtin_amdgcn_mfma_f32_32x32x16_bf16(kf, qf, z16, 0, 0, 0);
      u32 wr[8];
#pragma unroll
      for (int p = 0; p < 8; ++p)
        wr[p] = pack_bf(fexp2(d[2 * p]), fexp2(d[2 * p + 1]));
      const u16* va = vrow + it * 32;
      u32x4 af0 = *(const u32x4*)(va);        // ds_read_b128
      u32x4 af1 = *(const u32x4*)(va + 8);    // ds_read_b128 +16B
      u32x4 ef0 = {wr[0], wr[1], wr[2], wr[3]};
      u32x4 ef1 = {wr[4], wr[5], wr[6], wr[7]};
      acc = __builtin_amdgcn_mfma_f32_32x32x16_bf16(
          __builtin_bit_cast(bfrag, af0), __builtin_bit_cast(bfrag, ef0), acc, 0, 0, 0);
      acc = __builtin_amdgcn_mfma_f32_32x32x16_bf16(
          __builtin_bit_cast(bfrag, af1), __builtin_bit_cast(bfrag, ef1), acc, 0, 0, 0);
    }

    // write prefetched chunk into the other buffer
    if (ch < 3) {
      u16* dstb = &vls[(ch + 1) & 1][0][0];
#pragma unroll
      for (int kk = 0; kk < 4; ++kk) {
        int c = kk * 256 + tid;
        int tl = c >> 2, g = c & 3;
        float rc = rcs[(ch + 1) * 256 + tl];
        int i5 = tl >> 5, t5 = tl & 31;
        int sub = ((t5 >> 2) & 1) * 16 + ((t5 >> 3) << 2) + (t5 & 3);
        u16* wp = dstb + i5 * 32 + sub;
        wp[(4 * g + 0) * 264] = f2bf(pv[kk].x * rc);
        wp[(4 * g + 1) * 264] = f2bf(pv[kk].y * rc);
        wp[(4 * g + 2) * 264] = f2bf(pv[kk].z * rc);
        wp[(4 * g + 3) * 264] = f2bf(pv[kk].w * rc);
      }
    }
    __syncthreads();
  }

  // D[e][s]: col=l31 -> s; rows r=0..3 -> e=4hl+r, r=4..7 -> e=8+4hl+(r-4)
  float* ao = attp + (((size_t)tq * BB + b) * SS + s0 + l31) * (HH * HDD)
            + h * HDD + 4 * hl;
  float4 lo4 = {acc[0], acc[1], acc[2], acc[3]};
  float4 hi4 = {acc[4], acc[5], acc[6], acc[7]};
  *(float4*)ao       = lo4;
  *(float4*)(ao + 8) = hi4;
}

// ---------------------------------------------------------------------------
// K4: out_pre = (sum of 4 attended partials) @ Wo + bo, fused partial expsum
// over each block's 8 rows -> part[b][512][64].  Wo staged in LDS.
// ---------------------------------------------------------------------------
__global__ __launch_bounds__(256) void k_oproj(
    const float* __restrict__ att, const float* __restrict__ Wo,
    const float* __restrict__ bo, float* __restrict__ outp,
    float* __restrict__ part)
{
  __shared__ float wols[64 * 64];
  __shared__ float red[4][64];
  const int tid = threadIdx.x;
  const int blk = blockIdx.x;            // 2048
  const int b = blk >> 9, s0 = (blk & 511) << 3;
#pragma unroll
  for (int i = 0; i < 4; ++i)
    ((float4*)wols)[tid + 256 * i] = ((const float4*)Wo)[tid + 256 * i];
  __syncthreads();

  const int d = tid & 63, sg = tid >> 6;
  const float bov = bo[d];
  const size_t so = (size_t)BB * SS * 16;   // t-quarter stride in floatx4 units
  float es = 0.f;
#pragma unroll
  for (int r = 0; r < 2; ++r) {
    int s = s0 + sg * 2 + r;
    const floatx4* row = (const floatx4*)(att + ((size_t)b * SS + s) * 64);
    float acc = bov;
#pragma unroll
    for (int j = 0; j < 16; ++j) {
      floatx4 c = (row[j] + row[j + so]) + (row[j + 2 * so] + row[j + 3 * so]);
      acc += c[0] * wols[(4*j+0)*64 + d] + c[1] * wols[(4*j+1)*64 + d]
           + c[2] * wols[(4*j+2)*64 + d] + c[3] * wols[(4*j+3)*64 + d];
    }
    outp[((size_t)b * SS + s) * 64 + d] = acc;
    es += fexp2(acc * LOG2E);
  }
  red[sg][d] = es;
  __syncthreads();
  if (tid < 64)
    part[((size_t)b * 512 + (blk & 511)) * 64 + tid] =
        red[0][tid] + red[1][tid] + red[2][tid] + red[3][tid];
}

// ---------------------------------------------------------------------------
// K5: out = exp(out_pre) * rcp(sum_s exp(out_pre))  (512 partials per (b,d))
// ---------------------------------------------------------------------------
__global__ __launch_bounds__(256) void k_softmax(
    const float* __restrict__ outp, const float* __restrict__ part,
    float* __restrict__ out)
{
  __shared__ float red[4][64];
  __shared__ float rs[64];
  const int tid = threadIdx.x, d = tid & 63, sg = tid >> 6;
  const int st = blockIdx.x;             // 64 s-tiles of 64
  const int b = blockIdx.y;
  {
    float e = 0.f;
    const float* pp = part + ((size_t)b * 512 + sg * 128) * 64 + d;
#pragma unroll 8
    for (int c = 0; c < 128; ++c) e += pp[c * 64];
    red[sg][d] = e;
  }
  __syncthreads();
  if (tid < 64)
    rs[tid] = frcp(red[0][tid] + red[1][tid] + red[2][tid] + red[3][tid]);
  __syncthreads();
  const float r = rs[d];
  const size_t rowbase = ((size_t)b * SS + st * 64 + sg * 16) * 64 + d;
#pragma unroll 4
  for (int i = 0; i < 16; ++i)
    out[rowbase + i * 64] = fexp2(outp[rowbase + i * 64] * LOG2E) * r;
}

// ---------------------------------------------------------------------------
extern "C" void kernel_launch(void* const* d_in, const int* in_sizes, int n_in,
                              void* d_out, int out_size, void* d_ws, size_t ws_size,
                              hipStream_t stream) {
  const float* x  = (const float*)d_in[0];
  const float* Wq = (const float*)d_in[1];
  const float* bq = (const float*)d_in[2];
  const float* Wk = (const float*)d_in[3];
  const float* bk = (const float*)d_in[4];
  const float* Wv = (const float*)d_in[5];
  const float* bv = (const float*)d_in[6];
  const float* Wo = (const float*)d_in[7];
  const float* bo = (const float*)d_in[8];

  char* ws = (char*)d_ws;
  constexpr size_t QB_OFF  = 0;                    // 2 MiB u16
  constexpr size_t KB_OFF  = (size_t)2  << 20;     // 2 MiB u16
  constexpr size_t VF_OFF  = (size_t)4  << 20;     // 4 MiB f32
  constexpr size_t CSP_OFF = (size_t)10 << 20;     // 1 MiB f32 (4 partials)
  constexpr size_t ATT_OFF = (size_t)11 << 20;     // 16 MiB f32 (4 partials)
  constexpr size_t OUT_OFF = (size_t)27 << 20;     // 4 MiB f32
  constexpr size_t PT_OFF  = (size_t)31 << 20;     // 512 KiB f32

  u16*   qb   = (u16*)  (ws + QB_OFF);
  u16*   kb   = (u16*)  (ws + KB_OFF);
  float* vf   = (float*)(ws + VF_OFF);
  float* csp  = (float*)(ws + CSP_OFF);
  float* attp = (float*)(ws + ATT_OFF);
  float* outp = (float*)(ws + OUT_OFF);
  float* part = (float*)(ws + PT_OFF);
  float* out  = (float*)d_out;

  hipLaunchKernelGGL(k_proj,    dim3(1024),       dim3(256), 0, stream,
                     x, Wq, bq, Wk, bk, Wv, bv, qb, kb, vf);
  hipLaunchKernelGGL(k_colsum,  dim3(32, 4, 16),  dim3(256), 0, stream, qb, kb, csp);
  hipLaunchKernelGGL(k_attn,    dim3(32, 4, 16),  dim3(256), 0, stream,
                     qb, kb, vf, csp, attp);
  hipLaunchKernelGGL(k_oproj,   dim3(2048),       dim3(256), 0, stream,
                     attp, Wo, bo, outp, part);
  hipLaunchKernelGGL(k_softmax, dim3(64, 4),      dim3(256), 0, stream, outp, part, out);
}

// Round 9
// 185.910 us; speedup vs baseline: 1.1339x; 1.1339x over previous
//
#include <hip/hip_runtime.h>
#include <hip/hip_bf16.h>

// MultiHeadAttention B=4,S=4096,D=64,H=4,HD=16 on gfx950.
// softmax over QUERY axis => w[s,t] = E[s,t]/colsum[t], attended = E @ (V/colsum).
// Two MFMA passes recompute E (raw v_exp_f32).  Scores via 32x32x16 bf16 MFMA
// (K=16=HD exact).  PV consumes E directly as the B-operand; the implied k->t
// permutation is absorbed by pre-permuting v' into LDS fragment layout.
// R9: attn = t-split 2 (grid 1024 = exact 4 blocks/CU, no 7+1 tail; attp 8MB)
// + register-prefetch double-buffered 256-t chunks (LDS 24.9KB, cap 6).
// oproj 2-partial.  colsum 4 accumulators.  Goal: surface k_colsum in top-5.

#define BB 4
#define SS 4096
#define DD 64
#define HH 4
#define HDD 16

typedef unsigned int u32;
typedef unsigned short u16;
typedef __attribute__((ext_vector_type(8))) short bfrag;     // 8 bf16
typedef __attribute__((ext_vector_type(4))) float floatx4;
typedef __attribute__((ext_vector_type(16))) float floatx16;
typedef __attribute__((ext_vector_type(2))) u32 u32x2;
typedef __attribute__((ext_vector_type(4))) u32 u32x4;

#define LOG2E 1.4426950408889634074f
#define QSCALE (LOG2E * 0.25f)

__device__ __forceinline__ float fexp2(float x) {   // raw v_exp_f32
#if __has_builtin(__builtin_amdgcn_exp2f)
  return __builtin_amdgcn_exp2f(x);
#else
  float r; asm("v_exp_f32 %0, %1" : "=v"(r) : "v"(x)); return r;
#endif
}
__device__ __forceinline__ float frcp(float x) {    // raw v_rcp_f32
#if __has_builtin(__builtin_amdgcn_rcpf)
  return __builtin_amdgcn_rcpf(x);
#else
  float r; asm("v_rcp_f32 %0, %1" : "=v"(r) : "v"(x)); return r;
#endif
}

__device__ __forceinline__ u16 f2bf(float f) {      // RNE
  u32 u = __builtin_bit_cast(u32, f);
  return (u16)((u + 0x7FFFu + ((u >> 16) & 1u)) >> 16);
}
// pack two fp32 -> bf16x2 by truncation (E>=0), single v_perm_b32
__device__ __forceinline__ u32 pack_bf(float lo, float hi) {
#if __has_builtin(__builtin_amdgcn_perm)
  return __builtin_amdgcn_perm(__builtin_bit_cast(u32, hi),
                               __builtin_bit_cast(u32, lo), 0x07060302u);
#else
  u32 a = __builtin_bit_cast(u32, lo);
  u32 b = __builtin_bit_cast(u32, hi);
  return (a >> 16) | (b & 0xFFFF0000u);
#endif
}

// ---------------------------------------------------------------------------
// K1: projections. x[B,S,64] -> q bf16 (scaled, bias folded), k bf16, v fp32;
// layout [B,H,S,16].
// ---------------------------------------------------------------------------
__global__ __launch_bounds__(256) void k_proj(
    const float* __restrict__ x,
    const float* __restrict__ Wq, const float* __restrict__ bq,
    const float* __restrict__ Wk, const float* __restrict__ bk,
    const float* __restrict__ Wv, const float* __restrict__ bv,
    u16* __restrict__ qb, u16* __restrict__ kb, float* __restrict__ vf)
{
  __shared__ float xs[16 * 64];
  const int tid = threadIdx.x;
  const int blk = blockIdx.x;            // B*S/16 = 1024
  const int b   = blk >> 8;
  const int s0  = (blk & 255) << 4;
  ((float4*)xs)[tid] = ((const float4*)(x + ((size_t)b * SS + s0) * DD))[tid];
  __syncthreads();

  const int col = tid & 63, h = col >> 4, e = col & 15;
  const int rg  = tid >> 6;              // wave id; 4 rows each
  float aq[4] = {0,0,0,0}, ak[4] = {0,0,0,0}, av[4] = {0,0,0,0};
  const int wofs = h * (DD * HDD) + e;
#pragma unroll 4
  for (int d = 0; d < DD; ++d) {
    float wq = Wq[wofs + d * HDD];
    float wk = Wk[wofs + d * HDD];
    float wv = Wv[wofs + d * HDD];
    const float* xr = xs + (rg * 4) * 64 + d;
#pragma unroll
    for (int r = 0; r < 4; ++r) {
      float xv = xr[r * 64];
      aq[r] += xv * wq; ak[r] += xv * wk; av[r] += xv * wv;
    }
  }
  const float bqv = bq[col], bkv = bk[col], bvv = bv[col];
  size_t base = ((size_t)(b * HH + h) * SS + (s0 + rg * 4)) * HDD + e;
#pragma unroll
  for (int r = 0; r < 4; ++r) {
    qb[base + r * HDD] = f2bf((aq[r] + bqv) * QSCALE);
    kb[base + r * HDD] = f2bf(ak[r] + bkv);
    vf[base + r * HDD] = av[r] + bvv;
  }
}

// ---------------------------------------------------------------------------
// K2: partial colsums.  mfma(Q, K): D[m=s][n=t], col=lane&31 -> t, so the
// s-reduction is IN-LANE (4 parallel accumulators) + one shfl_xor(32).
// Wave owns 32 t; streams a 1024-s chunk.
// ---------------------------------------------------------------------------
__global__ __launch_bounds__(256, 8) void k_colsum(
    const u16* __restrict__ qb, const u16* __restrict__ kb,
    float* __restrict__ csp)
{
  const int tid = threadIdx.x;
  const int lane = tid & 63, w = tid >> 6;
  const int l31 = lane & 31, hl = lane >> 5;
  const int bh = blockIdx.z, chunk = blockIdx.y;
  const int t0 = blockIdx.x * 128 + w * 32;
  const size_t base = (size_t)bh * (SS * HDD);

  const bfrag kf = *(const bfrag*)(kb + base + (size_t)(t0 + l31) * HDD + hl * 8);
  const u16* qp = qb + base + (size_t)l31 * HDD + hl * 8;
  const floatx16 z16 = {0.f};
  float c0 = 0.f, c1 = 0.f, c2 = 0.f, c3 = 0.f;
  const int s0 = chunk * 1024;
#pragma unroll 2
  for (int s = s0; s < s0 + 1024; s += 32) {
    bfrag qfr = *(const bfrag*)(qp + (size_t)s * HDD);
    floatx16 d = __builtin_amdgcn_mfma_f32_32x32x16_bf16(qfr, kf, z16, 0, 0, 0);
#pragma unroll
    for (int i = 0; i < 4; ++i) {
      c0 += fexp2(d[4 * i + 0]);
      c1 += fexp2(d[4 * i + 1]);
      c2 += fexp2(d[4 * i + 2]);
      c3 += fexp2(d[4 * i + 3]);
    }
  }
  float c = (c0 + c1) + (c2 + c3);
  c += __shfl_xor(c, 32, 64);
  if (hl == 0)
    csp[((size_t)bh * 4 + chunk) * SS + t0 + l31] = c;
}

// ---------------------------------------------------------------------------
// K3: attended partials = E @ v' over a 2048-t half: eight 256-t chunks,
// DOUBLE-BUFFERED.  Per chunk: issue next chunk's global float4 loads into
// registers, compute 8 iters from the current LDS buffer, then scale+pack
// the prefetched regs into the other buffer; one barrier per chunk.
// rcs = rcp(colsum) built once per block for the whole half (8 KB LDS).
// LDS 24.9 KB -> capacity 6; grid 1024 = exact 4 blocks/CU, no tail.
// Inner loop per 32 t: 1 coalesced kf load, 1 score MFMA D'[t][s], 16 v_exp,
// 8 v_perm packs, 2 ds_read_b128, 2 PV MFMA.
// ---------------------------------------------------------------------------
__global__ __launch_bounds__(256, 4) void k_attn(
    const u16* __restrict__ qb, const u16* __restrict__ kb,
    const float* __restrict__ vf, const float* __restrict__ csp,
    float* __restrict__ attp)
{
  __shared__ __align__(16) u16 vls[2][16][264];    // 16,896 B (264 = 256+8 pad)
  __shared__ float rcs[2048];                      //  8,192 B
  const int tid  = threadIdx.x;
  const int lane = tid & 63, w = tid >> 6;
  const int l31 = lane & 31, hl = lane >> 5;
  const int bh = blockIdx.z, b = bh >> 2, h = bh & 3;
  const int tph = blockIdx.y;                      // 0..1
  const int s0 = blockIdx.x * 128 + w * 32;
  const size_t base = (size_t)bh * (SS * HDD);
  const int tbh = tph * 2048;

  // 1/colsum for the whole half (sum of 4 s-chunk partials)
  {
    const float* cp0 = csp + (size_t)bh * 4 * SS + tbh;
#pragma unroll
    for (int i = 0; i < 8; ++i) {
      int j = i * 256 + tid;
      rcs[j] = frcp(cp0[j] + cp0[j + SS] + cp0[j + 2 * SS] + cp0[j + 3 * SS]);
    }
  }
  __syncthreads();

  const bfrag qf = *(const bfrag*)(qb + base + (size_t)(s0 + l31) * HDD + hl * 8);
  const u16* kp = kb + base + (size_t)l31 * HDD + hl * 8;
  const floatx16 z16 = {0.f};
  floatx16 acc = {0.f};

  const float4* vsrc = (const float4*)(vf + base + (size_t)tbh * HDD);

  // stage chunk 0 into vls[0]
  {
#pragma unroll
    for (int kk = 0; kk < 4; ++kk) {
      int c = kk * 256 + tid;            // [0,1024): 256 t x 4 e-groups
      int tl = c >> 2, g = c & 3;
      float4 vv = vsrc[c];
      float rc = rcs[tl];
      int i5 = tl >> 5, t5 = tl & 31;
      int sub = ((t5 >> 2) & 1) * 16 + ((t5 >> 3) << 2) + (t5 & 3);
      u16* wp = &vls[0][0][0] + i5 * 32 + sub;
      wp[(4 * g + 0) * 264] = f2bf(vv.x * rc);
      wp[(4 * g + 1) * 264] = f2bf(vv.y * rc);
      wp[(4 * g + 2) * 264] = f2bf(vv.z * rc);
      wp[(4 * g + 3) * 264] = f2bf(vv.w * rc);
    }
  }
  __syncthreads();

#pragma unroll
  for (int ch = 0; ch < 8; ++ch) {
    // prefetch next chunk's global data into registers (issue before compute)
    float4 pv[4];
    if (ch < 7) {
#pragma unroll
      for (int kk = 0; kk < 4; ++kk)
        pv[kk] = vsrc[(ch + 1) * 1024 + kk * 256 + tid];
    }

    // compute 8 iters (256 t) from vls[ch&1]
    const u16* vrow = &vls[ch & 1][0][0] + (l31 & 15) * 264 + hl * 16;
    const int tb = tbh + ch * 256;
#pragma unroll 2
    for (int it = 0; it < 8; ++it) {
      bfrag kf = *(const bfrag*)(kp + (size_t)(tb + it * 32) * HDD);
      floatx16 d = __builtin_amdgcn_mfma_f32_32x32x16_bf16(kf, qf, z16, 0, 0, 0);
      u32 wr[8];
#pragma unroll
      for (int p = 0; p < 8; ++p)
        wr[p] = pack_bf(fexp2(d[2 * p]), fexp2(d[2 * p + 1]));
      const u16* va = vrow + it * 32;
      u32x4 af0 = *(const u32x4*)(va);        // ds_read_b128
      u32x4 af1 = *(const u32x4*)(va + 8);    // ds_read_b128 +16B
      u32x4 ef0 = {wr[0], wr[1], wr[2], wr[3]};
      u32x4 ef1 = {wr[4], wr[5], wr[6], wr[7]};
      acc = __builtin_amdgcn_mfma_f32_32x32x16_bf16(
          __builtin_bit_cast(bfrag, af0), __builtin_bit_cast(bfrag, ef0), acc, 0, 0, 0);
      acc = __builtin_amdgcn_mfma_f32_32x32x16_bf16(
          __builtin_bit_cast(bfrag, af1), __builtin_bit_cast(bfrag, ef1), acc, 0, 0, 0);
    }

    // write prefetched chunk into the other buffer
    if (ch < 7) {
      u16* dstb = &vls[(ch + 1) & 1][0][0];
#pragma unroll
      for (int kk = 0; kk < 4; ++kk) {
        int c = kk * 256 + tid;
        int tl = c >> 2, g = c & 3;
        float rc = rcs[(ch + 1) * 256 + tl];
        int i5 = tl >> 5, t5 = tl & 31;
        int sub = ((t5 >> 2) & 1) * 16 + ((t5 >> 3) << 2) + (t5 & 3);
        u16* wp = dstb + i5 * 32 + sub;
        wp[(4 * g + 0) * 264] = f2bf(pv[kk].x * rc);
        wp[(4 * g + 1) * 264] = f2bf(pv[kk].y * rc);
        wp[(4 * g + 2) * 264] = f2bf(pv[kk].z * rc);
        wp[(4 * g + 3) * 264] = f2bf(pv[kk].w * rc);
      }
    }
    __syncthreads();
  }

  // D[e][s]: col=l31 -> s; rows r=0..3 -> e=4hl+r, r=4..7 -> e=8+4hl+(r-4)
  float* ao = attp + (((size_t)tph * BB + b) * SS + s0 + l31) * (HH * HDD)
            + h * HDD + 4 * hl;
  float4 lo4 = {acc[0], acc[1], acc[2], acc[3]};
  float4 hi4 = {acc[4], acc[5], acc[6], acc[7]};
  *(float4*)ao       = lo4;
  *(float4*)(ao + 8) = hi4;
}

// ---------------------------------------------------------------------------
// K4: out_pre = (sum of 2 attended partials) @ Wo + bo, fused partial expsum
// over each block's 8 rows -> part[b][512][64].  Wo staged in LDS.
// ---------------------------------------------------------------------------
__global__ __launch_bounds__(256) void k_oproj(
    const float* __restrict__ att, const float* __restrict__ Wo,
    const float* __restrict__ bo, float* __restrict__ outp,
    float* __restrict__ part)
{
  __shared__ float wols[64 * 64];
  __shared__ float red[4][64];
  const int tid = threadIdx.x;
  const int blk = blockIdx.x;            // 2048
  const int b = blk >> 9, s0 = (blk & 511) << 3;
#pragma unroll
  for (int i = 0; i < 4; ++i)
    ((float4*)wols)[tid + 256 * i] = ((const float4*)Wo)[tid + 256 * i];
  __syncthreads();

  const int d = tid & 63, sg = tid >> 6;
  const float bov = bo[d];
  const size_t so = (size_t)BB * SS * 16;   // t-half stride in floatx4 units
  float es = 0.f;
#pragma unroll
  for (int r = 0; r < 2; ++r) {
    int s = s0 + sg * 2 + r;
    const floatx4* row = (const floatx4*)(att + ((size_t)b * SS + s) * 64);
    float acc = bov;
#pragma unroll
    for (int j = 0; j < 16; ++j) {
      floatx4 c = row[j] + row[j + so];
      acc += c[0] * wols[(4*j+0)*64 + d] + c[1] * wols[(4*j+1)*64 + d]
           + c[2] * wols[(4*j+2)*64 + d] + c[3] * wols[(4*j+3)*64 + d];
    }
    outp[((size_t)b * SS + s) * 64 + d] = acc;
    es += fexp2(acc * LOG2E);
  }
  red[sg][d] = es;
  __syncthreads();
  if (tid < 64)
    part[((size_t)b * 512 + (blk & 511)) * 64 + tid] =
        red[0][tid] + red[1][tid] + red[2][tid] + red[3][tid];
}

// ---------------------------------------------------------------------------
// K5: out = exp(out_pre) * rcp(sum_s exp(out_pre))  (512 partials per (b,d))
// ---------------------------------------------------------------------------
__global__ __launch_bounds__(256) void k_softmax(
    const float* __restrict__ outp, const float* __restrict__ part,
    float* __restrict__ out)
{
  __shared__ float red[4][64];
  __shared__ float rs[64];
  const int tid = threadIdx.x, d = tid & 63, sg = tid >> 6;
  const int st = blockIdx.x;             // 64 s-tiles of 64
  const int b = blockIdx.y;
  {
    float e = 0.f;
    const float* pp = part + ((size_t)b * 512 + sg * 128) * 64 + d;
#pragma unroll 8
    for (int c = 0; c < 128; ++c) e += pp[c * 64];
    red[sg][d] = e;
  }
  __syncthreads();
  if (tid < 64)
    rs[tid] = frcp(red[0][tid] + red[1][tid] + red[2][tid] + red[3][tid]);
  __syncthreads();
  const float r = rs[d];
  const size_t rowbase = ((size_t)b * SS + st * 64 + sg * 16) * 64 + d;
#pragma unroll 4
  for (int i = 0; i < 16; ++i)
    out[rowbase + i * 64] = fexp2(outp[rowbase + i * 64] * LOG2E) * r;
}

// ---------------------------------------------------------------------------
extern "C" void kernel_launch(void* const* d_in, const int* in_sizes, int n_in,
                              void* d_out, int out_size, void* d_ws, size_t ws_size,
                              hipStream_t stream) {
  const float* x  = (const float*)d_in[0];
  const float* Wq = (const float*)d_in[1];
  const float* bq = (const float*)d_in[2];
  const float* Wk = (const float*)d_in[3];
  const float* bk = (const float*)d_in[4];
  const float* Wv = (const float*)d_in[5];
  const float* bv = (const float*)d_in[6];
  const float* Wo = (const float*)d_in[7];
  const float* bo = (const float*)d_in[8];

  char* ws = (char*)d_ws;
  constexpr size_t QB_OFF  = 0;                    // 2 MiB u16
  constexpr size_t KB_OFF  = (size_t)2  << 20;     // 2 MiB u16
  constexpr size_t VF_OFF  = (size_t)4  << 20;     // 4 MiB f32
  constexpr size_t CSP_OFF = (size_t)10 << 20;     // 1 MiB f32 (4 partials)
  constexpr size_t ATT_OFF = (size_t)11 << 20;     // 8 MiB f32 (2 partials)
  constexpr size_t OUT_OFF = (size_t)27 << 20;     // 4 MiB f32
  constexpr size_t PT_OFF  = (size_t)31 << 20;     // 512 KiB f32

  u16*   qb   = (u16*)  (ws + QB_OFF);
  u16*   kb   = (u16*)  (ws + KB_OFF);
  float* vf   = (float*)(ws + VF_OFF);
  float* csp  = (float*)(ws + CSP_OFF);
  float* attp = (float*)(ws + ATT_OFF);
  float* outp = (float*)(ws + OUT_OFF);
  float* part = (float*)(ws + PT_OFF);
  float* out  = (float*)d_out;

  hipLaunchKernelGGL(k_proj,    dim3(1024),       dim3(256), 0, stream,
                     x, Wq, bq, Wk, bk, Wv, bv, qb, kb, vf);
  hipLaunchKernelGGL(k_colsum,  dim3(32, 4, 16),  dim3(256), 0, stream, qb, kb, csp);
  hipLaunchKernelGGL(k_attn,    dim3(32, 2, 16),  dim3(256), 0, stream,
                     qb, kb, vf, csp, attp);
  hipLaunchKernelGGL(k_oproj,   dim3(2048),       dim3(256), 0, stream,
                     attp, Wo, bo, outp, part);
  hipLaunchKernelGGL(k_softmax, dim3(64, 4),      dim3(256), 0, stream, outp, part, out);
}